// Round 1
// baseline (1521.727 us; speedup 1.0000x reference)
//
#include <hip/hip_runtime.h>
#include <cmath>

#define L_LEVELS 16
#define T_SIZE 524288u
#define T_MASK (T_SIZE - 1u)
#define P1 2654435761u
#define P2 805459861u

struct ResArr { int r[L_LEVELS]; };

// ---------------------------------------------------------------------------
// Single fused kernel: one thread per (point, level).
// grid = (npts/256, 16 levels), x-fastest dispatch order => the chip processes
// levels ~sequentially => each XCD's 4MB L2 holds exactly the current level's
// 4MB table => the 268M random 8B gathers hit L2 (~95%, verified by
// FETCH_SIZE=786MB vs 17GB of line-touches).
//
// Change vs previous round: write DIRECTLY to out[point][level] (float2,
// lane stride 128B) instead of a level-major ws + separate transpose pass.
// K1 is L2-request-rate bound (14.9 req/cy/XCD ~ the 16/cy channel limit),
// not BW bound (14% HBM), so the strided stores (+28M sector requests, ~+10%
// on the request budget, plus HBM write amplification on partial 64B lines)
// are cheaper than the transpose kernel's 512MB round-trip + 350us.
// ---------------------------------------------------------------------------
__global__ __launch_bounds__(256) void enc_level_direct_kernel(
    const float* __restrict__ x,
    const float* __restrict__ emb,
    float2* __restrict__ out,
    ResArr res, int npts)
{
    __shared__ float xsh[768];           // 256 points * 3 coords
    const int tid   = threadIdx.x;
    const int level = blockIdx.y;
    const int pbase = blockIdx.x * 256;

    // stage x: 192 float4 loads cover 768 floats, fully coalesced
    if (pbase + 256 <= npts) {
        if (tid < 192)
            ((float4*)xsh)[tid] = ((const float4*)(x + (size_t)pbase * 3))[tid];
    } else {
        const int nfl = npts * 3 - pbase * 3;
        for (int i = tid; i < nfl; i += 256) xsh[i] = x[(size_t)pbase * 3 + i];
    }
    __syncthreads();

    const int p = pbase + tid;
    if (p >= npts) return;

    // lds[3t+c]: 3t mod 32 covers all banks, 2 lanes/bank -> conflict-free
    const float px = xsh[tid * 3 + 0];
    const float py = xsh[tid * 3 + 1];
    const float pz = xsh[tid * 3 + 2];

    const float rf = (float)res.r[level];
    // single fp32 multiplies to bit-match reference rounding
    const float sx = px * rf, sy = py * rf, sz = pz * rf;
    const int ix = (int)sx, iy = (int)sy, iz = (int)sz;  // x>=0 -> trunc==floor
    const float fx = sx - (float)ix;
    const float fy = sy - (float)iy;
    const float fz = sz - (float)iz;

    // hash keeps only low 19 bits -> uint32 arithmetic exact vs int64 reference
    const unsigned hx0 = (unsigned)ix,      hx1 = hx0 + 1u;
    const unsigned hy0 = (unsigned)iy * P1, hy1 = hy0 + P1;
    const unsigned hz0 = (unsigned)iz * P2, hz1 = hz0 + P2;

    const unsigned h0 = (hx0 ^ hy0 ^ hz0) & T_MASK;
    const unsigned h1 = (hx0 ^ hy0 ^ hz1) & T_MASK;
    const unsigned h2 = (hx0 ^ hy1 ^ hz0) & T_MASK;
    const unsigned h3 = (hx0 ^ hy1 ^ hz1) & T_MASK;
    const unsigned h4 = (hx1 ^ hy0 ^ hz0) & T_MASK;
    const unsigned h5 = (hx1 ^ hy0 ^ hz1) & T_MASK;
    const unsigned h6 = (hx1 ^ hy1 ^ hz0) & T_MASK;
    const unsigned h7 = (hx1 ^ hy1 ^ hz1) & T_MASK;

    const float2* __restrict__ E = (const float2*)emb + (size_t)level * T_SIZE;
    const float2 c0v = E[h0];
    const float2 c1v = E[h1];
    const float2 c2v = E[h2];
    const float2 c3v = E[h3];
    const float2 c4v = E[h4];
    const float2 c5v = E[h5];
    const float2 c6v = E[h6];
    const float2 c7v = E[h7];

    const float gx = 1.0f - fx, gy = 1.0f - fy, gz = 1.0f - fz;
    // exact reference association: a*(1-f) + b*f
    const float c00x = c0v.x * gx + c4v.x * fx;
    const float c00y = c0v.y * gx + c4v.y * fx;
    const float c01x = c1v.x * gx + c5v.x * fx;
    const float c01y = c1v.y * gx + c5v.y * fx;
    const float c10x = c2v.x * gx + c6v.x * fx;
    const float c10y = c2v.y * gx + c6v.y * fx;
    const float c11x = c3v.x * gx + c7v.x * fx;
    const float c11y = c3v.y * gx + c7v.y * fx;

    const float a0x = c00x * gy + c10x * fy;
    const float a0y = c00y * gy + c10y * fy;
    const float a1x = c01x * gy + c11x * fy;
    const float a1y = c01y * gy + c11y * fy;

    // direct transposed store: out[point][level], float2.
    // 64 lanes -> 64 distinct 64B sectors (stride 128B); partial lines merge
    // in L2/L3 across level passes; we are request-bound, not BW-bound.
    out[(size_t)p * L_LEVELS + level] =
        make_float2(a0x * gz + a1x * fz, a0y * gz + a1y * fz);
}

extern "C" void kernel_launch(void* const* d_in, const int* in_sizes, int n_in,
                              void* d_out, int out_size, void* d_ws, size_t ws_size,
                              hipStream_t stream) {
    const float* x   = (const float*)d_in[0];
    const float* emb = (const float*)d_in[1];

    // Replicate Python: b = exp((log(2048)-log(16))/15); res_i = floor(16*b**i)
    // (host double math, bit-matching the reference; res[7] is ~153.996 so
    //  hardcoding is dangerous)
    ResArr res;
    const double b = exp((log(2048.0) - log(16.0)) / 15.0);
    for (int i = 0; i < L_LEVELS; ++i)
        res.r[i] = (int)floor(16.0 * pow(b, (double)i));

    const int npts = in_sizes[0] / 3;
    const int pblocks = (npts + 255) / 256;
    hipLaunchKernelGGL(enc_level_direct_kernel, dim3(pblocks, L_LEVELS), dim3(256),
                       0, stream, x, emb, (float2*)d_out, res, npts);
}

// Round 2
// 1272.105 us; speedup vs baseline: 1.1962x; 1.1962x over previous
//
#include <hip/hip_runtime.h>
#include <cmath>

#define L_LEVELS 16
#define T_SIZE 524288u
#define T_MASK (T_SIZE - 1u)
#define P1 2654435761u
#define P2 805459861u

struct ResArr { int r[L_LEVELS]; };

// ---------------------------------------------------------------------------
// K1: one thread per (point, level). grid = (npts/256, 16 levels), x-fastest
// dispatch order => chip processes levels ~sequentially => each XCD's 4MB L2
// holds exactly the current level's 4MB table => gathers hit L2 (~95%,
// FETCH=786MB vs 17GB of line-touches). At ~15 L2-req/cy/XCD this kernel is
// at the L2 lookup-rate roofline (268M irreducible random 8B gathers).
// Writes level-major ws[level][point]: wave writes 512B contiguous, full
// lines, no RFO. (Round-1 lesson: direct out[p][l] stores RFO'd + 4x write-
// amplified -> FETCH 1.9GB, +350us. Never partial-line scatter the output.)
// ---------------------------------------------------------------------------
__global__ __launch_bounds__(256) void enc_level_kernel(
    const float* __restrict__ x,
    const float* __restrict__ emb,
    float2* __restrict__ ws,
    ResArr res, int npts)
{
    __shared__ float xsh[768];           // 256 points * 3 coords
    const int tid   = threadIdx.x;
    const int level = blockIdx.y;
    const int pbase = blockIdx.x * 256;

    // stage x: 192 float4 loads cover 768 floats, fully coalesced
    if (pbase + 256 <= npts) {
        if (tid < 192)
            ((float4*)xsh)[tid] = ((const float4*)(x + (size_t)pbase * 3))[tid];
    } else {
        const int nfl = npts * 3 - pbase * 3;
        for (int i = tid; i < nfl; i += 256) xsh[i] = x[(size_t)pbase * 3 + i];
    }
    __syncthreads();

    const int p = pbase + tid;
    if (p >= npts) return;

    // lds[3t+c]: 3t mod 32 covers all banks, 2 lanes/bank -> conflict-free
    const float px = xsh[tid * 3 + 0];
    const float py = xsh[tid * 3 + 1];
    const float pz = xsh[tid * 3 + 2];

    const float rf = (float)res.r[level];
    // single fp32 multiplies to bit-match reference rounding
    const float sx = px * rf, sy = py * rf, sz = pz * rf;
    const int ix = (int)sx, iy = (int)sy, iz = (int)sz;  // x>=0 -> trunc==floor
    const float fx = sx - (float)ix;
    const float fy = sy - (float)iy;
    const float fz = sz - (float)iz;

    // hash keeps only low 19 bits -> uint32 arithmetic exact vs int64 reference
    const unsigned hx0 = (unsigned)ix,      hx1 = hx0 + 1u;
    const unsigned hy0 = (unsigned)iy * P1, hy1 = hy0 + P1;
    const unsigned hz0 = (unsigned)iz * P2, hz1 = hz0 + P2;

    const unsigned h0 = (hx0 ^ hy0 ^ hz0) & T_MASK;
    const unsigned h1 = (hx0 ^ hy0 ^ hz1) & T_MASK;
    const unsigned h2 = (hx0 ^ hy1 ^ hz0) & T_MASK;
    const unsigned h3 = (hx0 ^ hy1 ^ hz1) & T_MASK;
    const unsigned h4 = (hx1 ^ hy0 ^ hz0) & T_MASK;
    const unsigned h5 = (hx1 ^ hy0 ^ hz1) & T_MASK;
    const unsigned h6 = (hx1 ^ hy1 ^ hz0) & T_MASK;
    const unsigned h7 = (hx1 ^ hy1 ^ hz1) & T_MASK;

    const float2* __restrict__ E = (const float2*)emb + (size_t)level * T_SIZE;
    const float2 c0v = E[h0];
    const float2 c1v = E[h1];
    const float2 c2v = E[h2];
    const float2 c3v = E[h3];
    const float2 c4v = E[h4];
    const float2 c5v = E[h5];
    const float2 c6v = E[h6];
    const float2 c7v = E[h7];

    const float gx = 1.0f - fx, gy = 1.0f - fy, gz = 1.0f - fz;
    // exact reference association: a*(1-f) + b*f
    const float c00x = c0v.x * gx + c4v.x * fx;
    const float c00y = c0v.y * gx + c4v.y * fx;
    const float c01x = c1v.x * gx + c5v.x * fx;
    const float c01y = c1v.y * gx + c5v.y * fx;
    const float c10x = c2v.x * gx + c6v.x * fx;
    const float c10y = c2v.y * gx + c6v.y * fx;
    const float c11x = c3v.x * gx + c7v.x * fx;
    const float c11y = c3v.y * gx + c7v.y * fx;

    const float a0x = c00x * gy + c10x * fy;
    const float a0y = c00y * gy + c10y * fy;
    const float a1x = c01x * gy + c11x * fy;
    const float a1y = c01y * gy + c11y * fy;

    ws[(size_t)level * npts + p] =
        make_float2(a0x * gz + a1x * fz, a0y * gz + a1y * fz);
}

// ---------------------------------------------------------------------------
// K2 (rewritten): LDS-tiled transpose ws[level][point] -> out[point][level].
// Old K2 ran at 1.5 TB/s: its loads were lane-INTERLEAVED (lane t, t+1 16MB
// apart; same-sector lanes 8 apart) => TA didn't merge => ~64M 8B requests.
// New scheme, block = 256 threads = 256-point tile:
//   load : 16 passes, thread t loads ws[l*npts + pbase+t] -> 512B contiguous
//          per wave per instr (8 full 64B sectors).
//   LDS  : tile[t*17 + l], pad-17 float2 rows.
//          write bank = (2t+2l)&31 -> 2 lanes/bank -> free.
//          read  bank = (2s+4k)&31 -> <=4-way -> 1.6x on LDS only, hidden.
//   store: thread t stores out4[pbase*8 + i*256 + t] -> 1KB contiguous per
//          wave per instr, full lines, no RFO.
// ---------------------------------------------------------------------------
__global__ __launch_bounds__(256) void transpose_tile_kernel(
    const float2* __restrict__ ws, float4* __restrict__ out4, int npts)
{
    __shared__ float2 tile[256 * 17];    // 34816 B -> 4 blocks/CU (16 waves)
    const int t     = threadIdx.x;
    const int pbase = blockIdx.x * 256;

    if (pbase + 256 <= npts) {
        #pragma unroll
        for (int l = 0; l < L_LEVELS; ++l)
            tile[t * 17 + l] = ws[(size_t)l * npts + pbase + t];
        __syncthreads();

        #pragma unroll
        for (int i = 0; i < 8; ++i) {
            const int jl = i * 256 + t;          // local float4 index
            const int pl = jl >> 3;              // local point
            const int k  = jl & 7;               // float4 within point
            const float2 a = tile[pl * 17 + 2 * k];
            const float2 b = tile[pl * 17 + 2 * k + 1];
            out4[(size_t)pbase * 8 + jl] = make_float4(a.x, a.y, b.x, b.y);
        }
    } else {
        // guarded tail tile
        const int p = pbase + t;
        if (p < npts) {
            #pragma unroll
            for (int l = 0; l < L_LEVELS; ++l)
                tile[t * 17 + l] = ws[(size_t)l * npts + p];
        }
        __syncthreads();
        const int npts_loc = npts - pbase;       // valid points in tile
        for (int i = 0; i < 8; ++i) {
            const int jl = i * 256 + t;
            const int pl = jl >> 3;
            const int k  = jl & 7;
            if (pl < npts_loc) {
                const float2 a = tile[pl * 17 + 2 * k];
                const float2 b = tile[pl * 17 + 2 * k + 1];
                out4[(size_t)pbase * 8 + jl] = make_float4(a.x, a.y, b.x, b.y);
            }
        }
    }
}

// ---------------------------------------------------------------------------
// Fallback: used only if ws_size is too small for the 256MB level-major
// intermediate. One thread per (point, level), 16 lanes = 16 levels of one
// point, coalesced float2 output.
// ---------------------------------------------------------------------------
__global__ __launch_bounds__(256) void hash_enc_fallback(
    const float* __restrict__ x,
    const float* __restrict__ emb,
    float* __restrict__ out,
    ResArr res, int npts)
{
    __shared__ float xsh[48];
    const int tid = threadIdx.x;
    const int blockPointBase = blockIdx.x * 16;
    if (tid < 48) xsh[tid] = x[(size_t)blockPointBase * 3 + tid];
    __syncthreads();

    const int lp    = tid >> 4;
    const int level = tid & 15;
    const int p     = blockPointBase + lp;
    if (p >= npts) return;

    const float px = xsh[lp * 3 + 0];
    const float py = xsh[lp * 3 + 1];
    const float pz = xsh[lp * 3 + 2];

    const float rf = (float)res.r[level];
    const float sx = px * rf, sy = py * rf, sz = pz * rf;
    const int ix = (int)sx, iy = (int)sy, iz = (int)sz;
    const float fx = sx - (float)ix;
    const float fy = sy - (float)iy;
    const float fz = sz - (float)iz;

    const unsigned hx0 = (unsigned)ix,      hx1 = hx0 + 1u;
    const unsigned hy0 = (unsigned)iy * P1, hy1 = hy0 + P1;
    const unsigned hz0 = (unsigned)iz * P2, hz1 = hz0 + P2;

    const unsigned h0 = (hx0 ^ hy0 ^ hz0) & T_MASK;
    const unsigned h1 = (hx0 ^ hy0 ^ hz1) & T_MASK;
    const unsigned h2 = (hx0 ^ hy1 ^ hz0) & T_MASK;
    const unsigned h3 = (hx0 ^ hy1 ^ hz1) & T_MASK;
    const unsigned h4 = (hx1 ^ hy0 ^ hz0) & T_MASK;
    const unsigned h5 = (hx1 ^ hy0 ^ hz1) & T_MASK;
    const unsigned h6 = (hx1 ^ hy1 ^ hz0) & T_MASK;
    const unsigned h7 = (hx1 ^ hy1 ^ hz1) & T_MASK;

    const float2* __restrict__ E = (const float2*)emb + (size_t)level * T_SIZE;
    const float2 c0v = E[h0];
    const float2 c1v = E[h1];
    const float2 c2v = E[h2];
    const float2 c3v = E[h3];
    const float2 c4v = E[h4];
    const float2 c5v = E[h5];
    const float2 c6v = E[h6];
    const float2 c7v = E[h7];

    const float gx = 1.0f - fx, gy = 1.0f - fy, gz = 1.0f - fz;
    const float c00x = c0v.x * gx + c4v.x * fx;
    const float c00y = c0v.y * gx + c4v.y * fx;
    const float c01x = c1v.x * gx + c5v.x * fx;
    const float c01y = c1v.y * gx + c5v.y * fx;
    const float c10x = c2v.x * gx + c6v.x * fx;
    const float c10y = c2v.y * gx + c6v.y * fx;
    const float c11x = c3v.x * gx + c7v.x * fx;
    const float c11y = c3v.y * gx + c7v.y * fx;

    const float a0x = c00x * gy + c10x * fy;
    const float a0y = c00y * gy + c10y * fy;
    const float a1x = c01x * gy + c11x * fy;
    const float a1y = c01y * gy + c11y * fy;

    ((float2*)out)[(size_t)p * 16 + level] =
        make_float2(a0x * gz + a1x * fz, a0y * gz + a1y * fz);
}

extern "C" void kernel_launch(void* const* d_in, const int* in_sizes, int n_in,
                              void* d_out, int out_size, void* d_ws, size_t ws_size,
                              hipStream_t stream) {
    const float* x   = (const float*)d_in[0];
    const float* emb = (const float*)d_in[1];

    // Replicate Python: b = exp((log(2048)-log(16))/15); res_i = floor(16*b**i)
    ResArr res;
    const double b = exp((log(2048.0) - log(16.0)) / 15.0);
    for (int i = 0; i < L_LEVELS; ++i)
        res.r[i] = (int)floor(16.0 * pow(b, (double)i));

    const int npts = in_sizes[0] / 3;
    const size_t ws_needed = (size_t)npts * L_LEVELS * sizeof(float2);

    if (ws_size >= ws_needed) {
        float2* ws = (float2*)d_ws;
        const int pblocks = (npts + 255) / 256;
        hipLaunchKernelGGL(enc_level_kernel, dim3(pblocks, L_LEVELS), dim3(256),
                           0, stream, x, emb, ws, res, npts);
        hipLaunchKernelGGL(transpose_tile_kernel, dim3(pblocks), dim3(256),
                           0, stream, ws, (float4*)d_out, npts);
    } else {
        const int blocks = (npts + 15) / 16;
        hipLaunchKernelGGL(hash_enc_fallback, dim3(blocks), dim3(256),
                           0, stream, x, emb, (float*)d_out, res, npts);
    }
}

// Round 3
// 1197.837 us; speedup vs baseline: 1.2704x; 1.0620x over previous
//
#include <hip/hip_runtime.h>
#include <cmath>

#define L_LEVELS 16
#define T_SIZE 524288u
#define T_MASK (T_SIZE - 1u)
#define P1 2654435761u
#define P2 805459861u

struct ResArr { int r[L_LEVELS]; };

// ---------------------------------------------------------------------------
// K1: one thread per (point, level). grid = (npts/256, 16 levels), x-fastest
// dispatch order => chip processes levels ~sequentially => each XCD's 4MB L2
// holds the current level's 4MB table => gathers hit L2 (~95%, FETCH=786MB).
// K1 is L2 lookup-rate bound (~15 req/cy/XCD vs 16 channels).
//
// Round-3 change: corner-pair x-compression. Corners j and j+4 differ only
// in the x cell: h_{j+4} = h_j ^ diffx, diffx = hx0^(hx0+1) in {1,3,7,...}.
// If ix even (p=1/2): diffx==1, the pair {h, h^1} is ONE aligned float4 ->
// one 16B load serves both corners. Else a second float2 load, exec-masked
// (masked lanes issue no L2 request). Gathers/point: 8 -> 6 (-25% requests).
//
// (Round-1 lesson: never partial-line scatter the output -> RFO + 4x write
// amplification. ws stays level-major, full-line wave stores.)
// ---------------------------------------------------------------------------
__global__ __launch_bounds__(256) void enc_level_kernel(
    const float* __restrict__ x,
    const float* __restrict__ emb,
    float2* __restrict__ ws,
    ResArr res, int npts)
{
    __shared__ float xsh[768];           // 256 points * 3 coords
    const int tid   = threadIdx.x;
    const int level = blockIdx.y;
    const int pbase = blockIdx.x * 256;

    // stage x: 192 float4 loads cover 768 floats, fully coalesced
    if (pbase + 256 <= npts) {
        if (tid < 192)
            ((float4*)xsh)[tid] = ((const float4*)(x + (size_t)pbase * 3))[tid];
    } else {
        const int nfl = npts * 3 - pbase * 3;
        for (int i = tid; i < nfl; i += 256) xsh[i] = x[(size_t)pbase * 3 + i];
    }
    __syncthreads();

    const int p = pbase + tid;
    if (p >= npts) return;

    // lds[3t+c]: 3t mod 32 covers all banks, 2 lanes/bank -> conflict-free
    const float px = xsh[tid * 3 + 0];
    const float py = xsh[tid * 3 + 1];
    const float pz = xsh[tid * 3 + 2];

    const float rf = (float)res.r[level];
    // single fp32 multiplies to bit-match reference rounding
    const float sx = px * rf, sy = py * rf, sz = pz * rf;
    const int ix = (int)sx, iy = (int)sy, iz = (int)sz;  // x>=0 -> trunc==floor
    const float fx = sx - (float)ix;
    const float fy = sy - (float)iy;
    const float fz = sz - (float)iz;

    // hash keeps only low 19 bits -> uint32 arithmetic exact vs int64 reference
    const unsigned hx0 = (unsigned)ix,      hx1 = hx0 + 1u;
    const unsigned hy0 = (unsigned)iy * P1, hy1 = hy0 + P1;
    const unsigned hz0 = (unsigned)iz * P2, hz1 = hz0 + P2;

    // diffx = hx0 ^ (hx0+1) = 2^(trailing_ones(hx0)+1) - 1; < 2^19 since
    // ix <= 2048, so xor with an &T_MASK'd hash stays in range.
    const unsigned diffx = hx0 ^ hx1;

    const unsigned h0 = (hx0 ^ hy0 ^ hz0) & T_MASK;
    const unsigned h1 = (hx0 ^ hy0 ^ hz1) & T_MASK;
    const unsigned h2 = (hx0 ^ hy1 ^ hz0) & T_MASK;
    const unsigned h3 = (hx0 ^ hy1 ^ hz1) & T_MASK;

    const float2* __restrict__ E  = (const float2*)emb + (size_t)level * T_SIZE;
    const float4* __restrict__ E4 = (const float4*)E;   // 2 slots per float4

    // One aligned float4 per pair: slots {h&~1, h|1}.
    const float4 v0 = E4[h0 >> 1];
    const float4 v1 = E4[h1 >> 1];
    const float4 v2 = E4[h2 >> 1];
    const float4 v3 = E4[h3 >> 1];

    const bool odd0 = (h0 & 1u), odd1 = (h1 & 1u), odd2 = (h2 & 1u), odd3 = (h3 & 1u);
    const float2 c0v = odd0 ? make_float2(v0.z, v0.w) : make_float2(v0.x, v0.y);
    const float2 c1v = odd1 ? make_float2(v1.z, v1.w) : make_float2(v1.x, v1.y);
    const float2 c2v = odd2 ? make_float2(v2.z, v2.w) : make_float2(v2.x, v2.y);
    const float2 c3v = odd3 ? make_float2(v3.z, v3.w) : make_float2(v3.x, v3.y);

    // partner corner (x+1): valid from v* iff diffx==1 (then h^1 = other half)
    float2 c4v = odd0 ? make_float2(v0.x, v0.y) : make_float2(v0.z, v0.w);
    float2 c5v = odd1 ? make_float2(v1.x, v1.y) : make_float2(v1.z, v1.w);
    float2 c6v = odd2 ? make_float2(v2.x, v2.y) : make_float2(v2.z, v2.w);
    float2 c7v = odd3 ? make_float2(v3.x, v3.y) : make_float2(v3.z, v3.w);
    if (diffx != 1u) {          // ~half the lanes; masked lanes issue no requests
        c4v = E[h0 ^ diffx];
        c5v = E[h1 ^ diffx];
        c6v = E[h2 ^ diffx];
        c7v = E[h3 ^ diffx];
    }

    const float gx = 1.0f - fx, gy = 1.0f - fy, gz = 1.0f - fz;
    // exact reference association: a*(1-f) + b*f
    const float c00x = c0v.x * gx + c4v.x * fx;
    const float c00y = c0v.y * gx + c4v.y * fx;
    const float c01x = c1v.x * gx + c5v.x * fx;
    const float c01y = c1v.y * gx + c5v.y * fx;
    const float c10x = c2v.x * gx + c6v.x * fx;
    const float c10y = c2v.y * gx + c6v.y * fx;
    const float c11x = c3v.x * gx + c7v.x * fx;
    const float c11y = c3v.y * gx + c7v.y * fx;

    const float a0x = c00x * gy + c10x * fy;
    const float a0y = c00y * gy + c10y * fy;
    const float a1x = c01x * gy + c11x * fy;
    const float a1y = c01y * gy + c11y * fy;

    ws[(size_t)level * npts + p] =
        make_float2(a0x * gz + a1x * fz, a0y * gz + a1y * fz);
}

// ---------------------------------------------------------------------------
// K2: LDS-tiled transpose ws[level][point] -> out[point][level].
// Measured ~107us (512MB at ~4.8 TB/s effective) once the ~225us fixed graph
// overhead is accounted for. Near roofline; unchanged this round.
//   load : 16 passes, thread t loads ws[l*npts + pbase+t] -> 512B/wave/instr.
//   LDS  : tile[t*17 + l] pad-17 float2 rows (write 2-way=free, read <=4-way).
//   store: 1KB/wave/instr contiguous float4, full lines, no RFO.
// ---------------------------------------------------------------------------
__global__ __launch_bounds__(256) void transpose_tile_kernel(
    const float2* __restrict__ ws, float4* __restrict__ out4, int npts)
{
    __shared__ float2 tile[256 * 17];    // 34816 B -> 4 blocks/CU (16 waves)
    const int t     = threadIdx.x;
    const int pbase = blockIdx.x * 256;

    if (pbase + 256 <= npts) {
        #pragma unroll
        for (int l = 0; l < L_LEVELS; ++l)
            tile[t * 17 + l] = ws[(size_t)l * npts + pbase + t];
        __syncthreads();

        #pragma unroll
        for (int i = 0; i < 8; ++i) {
            const int jl = i * 256 + t;          // local float4 index
            const int pl = jl >> 3;              // local point
            const int k  = jl & 7;               // float4 within point
            const float2 a = tile[pl * 17 + 2 * k];
            const float2 b = tile[pl * 17 + 2 * k + 1];
            out4[(size_t)pbase * 8 + jl] = make_float4(a.x, a.y, b.x, b.y);
        }
    } else {
        // guarded tail tile
        const int p = pbase + t;
        if (p < npts) {
            #pragma unroll
            for (int l = 0; l < L_LEVELS; ++l)
                tile[t * 17 + l] = ws[(size_t)l * npts + p];
        }
        __syncthreads();
        const int npts_loc = npts - pbase;       // valid points in tile
        for (int i = 0; i < 8; ++i) {
            const int jl = i * 256 + t;
            const int pl = jl >> 3;
            const int k  = jl & 7;
            if (pl < npts_loc) {
                const float2 a = tile[pl * 17 + 2 * k];
                const float2 b = tile[pl * 17 + 2 * k + 1];
                out4[(size_t)pbase * 8 + jl] = make_float4(a.x, a.y, b.x, b.y);
            }
        }
    }
}

// ---------------------------------------------------------------------------
// Fallback: used only if ws_size is too small for the 256MB level-major
// intermediate. One thread per (point, level), 16 lanes = 16 levels of one
// point, coalesced float2 output.
// ---------------------------------------------------------------------------
__global__ __launch_bounds__(256) void hash_enc_fallback(
    const float* __restrict__ x,
    const float* __restrict__ emb,
    float* __restrict__ out,
    ResArr res, int npts)
{
    __shared__ float xsh[48];
    const int tid = threadIdx.x;
    const int blockPointBase = blockIdx.x * 16;
    if (tid < 48) xsh[tid] = x[(size_t)blockPointBase * 3 + tid];
    __syncthreads();

    const int lp    = tid >> 4;
    const int level = tid & 15;
    const int p     = blockPointBase + lp;
    if (p >= npts) return;

    const float px = xsh[lp * 3 + 0];
    const float py = xsh[lp * 3 + 1];
    const float pz = xsh[lp * 3 + 2];

    const float rf = (float)res.r[level];
    const float sx = px * rf, sy = py * rf, sz = pz * rf;
    const int ix = (int)sx, iy = (int)sy, iz = (int)sz;
    const float fx = sx - (float)ix;
    const float fy = sy - (float)iy;
    const float fz = sz - (float)iz;

    const unsigned hx0 = (unsigned)ix,      hx1 = hx0 + 1u;
    const unsigned hy0 = (unsigned)iy * P1, hy1 = hy0 + P1;
    const unsigned hz0 = (unsigned)iz * P2, hz1 = hz0 + P2;

    const unsigned h0 = (hx0 ^ hy0 ^ hz0) & T_MASK;
    const unsigned h1 = (hx0 ^ hy0 ^ hz1) & T_MASK;
    const unsigned h2 = (hx0 ^ hy1 ^ hz0) & T_MASK;
    const unsigned h3 = (hx0 ^ hy1 ^ hz1) & T_MASK;
    const unsigned h4 = (hx1 ^ hy0 ^ hz0) & T_MASK;
    const unsigned h5 = (hx1 ^ hy0 ^ hz1) & T_MASK;
    const unsigned h6 = (hx1 ^ hy1 ^ hz0) & T_MASK;
    const unsigned h7 = (hx1 ^ hy1 ^ hz1) & T_MASK;

    const float2* __restrict__ E = (const float2*)emb + (size_t)level * T_SIZE;
    const float2 c0v = E[h0];
    const float2 c1v = E[h1];
    const float2 c2v = E[h2];
    const float2 c3v = E[h3];
    const float2 c4v = E[h4];
    const float2 c5v = E[h5];
    const float2 c6v = E[h6];
    const float2 c7v = E[h7];

    const float gx = 1.0f - fx, gy = 1.0f - fy, gz = 1.0f - fz;
    const float c00x = c0v.x * gx + c4v.x * fx;
    const float c00y = c0v.y * gx + c4v.y * fx;
    const float c01x = c1v.x * gx + c5v.x * fx;
    const float c01y = c1v.y * gx + c5v.y * fx;
    const float c10x = c2v.x * gx + c6v.x * fx;
    const float c10y = c2v.y * gx + c6v.y * fx;
    const float c11x = c3v.x * gx + c7v.x * fx;
    const float c11y = c3v.y * gx + c7v.y * fx;

    const float a0x = c00x * gy + c10x * fy;
    const float a0y = c00y * gy + c10y * fy;
    const float a1x = c01x * gy + c11x * fy;
    const float a1y = c01y * gy + c11y * fy;

    ((float2*)out)[(size_t)p * 16 + level] =
        make_float2(a0x * gz + a1x * fz, a0y * gz + a1y * fz);
}

extern "C" void kernel_launch(void* const* d_in, const int* in_sizes, int n_in,
                              void* d_out, int out_size, void* d_ws, size_t ws_size,
                              hipStream_t stream) {
    const float* x   = (const float*)d_in[0];
    const float* emb = (const float*)d_in[1];

    // Replicate Python: b = exp((log(2048)-log(16))/15); res_i = floor(16*b**i)
    ResArr res;
    const double b = exp((log(2048.0) - log(16.0)) / 15.0);
    for (int i = 0; i < L_LEVELS; ++i)
        res.r[i] = (int)floor(16.0 * pow(b, (double)i));

    const int npts = in_sizes[0] / 3;
    const size_t ws_needed = (size_t)npts * L_LEVELS * sizeof(float2);

    if (ws_size >= ws_needed) {
        float2* ws = (float2*)d_ws;
        const int pblocks = (npts + 255) / 256;
        hipLaunchKernelGGL(enc_level_kernel, dim3(pblocks, L_LEVELS), dim3(256),
                           0, stream, x, emb, ws, res, npts);
        hipLaunchKernelGGL(transpose_tile_kernel, dim3(pblocks), dim3(256),
                           0, stream, ws, (float4*)d_out, npts);
    } else {
        const int blocks = (npts + 15) / 16;
        hipLaunchKernelGGL(hash_enc_fallback, dim3(blocks), dim3(256),
                           0, stream, x, emb, (float*)d_out, res, npts);
    }
}